// Round 8
// baseline (67.964 us; speedup 1.0000x reference)
//
#include <hip/hip_runtime.h>
#include <math.h>

#define NTX_EPS 1e-8f

typedef __fp16 half8 __attribute__((ext_vector_type(8)));
typedef __fp16 half2v __attribute__((ext_vector_type(2)));
typedef float f32x4 __attribute__((ext_vector_type(4)));

union H8 { half8 v8; half2v v2[4]; };

__device__ __forceinline__ half8 pack8(const float4& a, const float4& b) {
    H8 u;
    u.v2[0] = __builtin_amdgcn_cvt_pkrtz(a.x, a.y);
    u.v2[1] = __builtin_amdgcn_cvt_pkrtz(a.z, a.w);
    u.v2[2] = __builtin_amdgcn_cvt_pkrtz(b.x, b.y);
    u.v2[3] = __builtin_amdgcn_cvt_pkrtz(b.z, b.w);
    return u.v8;
}

// Kernel 1: 1792 blocks x 256 threads (4 waves). Block = (b, slot):
// slot 0..3 -> lvl0 d-range slot*1024; 4..5 -> lvl1; 6 -> lvl2.
// Wave w owns d-sub-range w*256..+255 (8 K-steps of 32). Register-only MFMA
// Gram (R7-verified: absmax 0): lane l loads ts[l&15][.. + (l>>4)*8 .. +7],
// one f16x8 register serves as both A and B operand; mfma(t,t)/(t,r)/(r,r).
// R7 counters (VALU 2%, Mfma 1%, occ 16%, 32 VGPR) => latency-bound, too few
// waves + depth-1 prefetch. This round: 4x waves + depth-2 staging (8 loads
// = 8KB in flight per wave), 4-wave LDS reduce in epilogue.
__global__ __launch_bounds__(256)
void ntxent_partial(const float* __restrict__ ts0, const float* __restrict__ rs0,
                    const float* __restrict__ ts1, const float* __restrict__ rs1,
                    const float* __restrict__ ts2, const float* __restrict__ rs2,
                    float* __restrict__ ws, float* __restrict__ out)
{
    __shared__ float redTT[4][256];
    __shared__ float redTR[4][256];
    __shared__ float redRR[4][16];
    __shared__ float Gs[16][33];
    __shared__ float rn2[16], tnS[16], rnS[16];

    const int bid  = blockIdx.x;
    const int b    = bid / 7;
    const int slot = bid % 7;

    const float* tp; const float* rp; int D; int chunk0;
    if (slot < 4)      { tp = ts0; rp = rs0; D = 4096; chunk0 = slot; }
    else if (slot < 6) { tp = ts1; rp = rs1; D = 2048; chunk0 = slot - 4; }
    else               { tp = ts2; rp = rs2; D = 1024; chunk0 = 0; }

    const int t   = threadIdx.x;
    const int w   = t >> 6;       // wave 0..3
    const int l   = t & 63;
    const int row = l & 15;       // Gram row/col this lane feeds
    const int kg  = l >> 4;       // k-group 0..3

    const size_t base = (size_t)b * 16 * D + (size_t)row * D
                      + (size_t)chunk0 * 1024 + (size_t)w * 256 + (size_t)kg * 8;
    const float* tsrc = tp + base;
    const float* rsrc = rp + base;

    f32x4 acc_tt = {0.f, 0.f, 0.f, 0.f};
    f32x4 acc_tr = {0.f, 0.f, 0.f, 0.f};
    f32x4 acc_rr = {0.f, 0.f, 0.f, 0.f};

    // depth-2 register staging; loop fully unrolled so stg indices are static
    float4 stg[2][4];
#pragma unroll
    for (int p = 0; p < 2; ++p) {
        stg[p][0] = *(const float4*)(tsrc + p * 32);
        stg[p][1] = *(const float4*)(tsrc + p * 32 + 4);
        stg[p][2] = *(const float4*)(rsrc + p * 32);
        stg[p][3] = *(const float4*)(rsrc + p * 32 + 4);
    }
#pragma unroll
    for (int s = 0; s < 8; ++s) {
        half8 tf = pack8(stg[s & 1][0], stg[s & 1][1]);
        half8 rf = pack8(stg[s & 1][2], stg[s & 1][3]);
        if (s + 2 < 8) {
            stg[s & 1][0] = *(const float4*)(tsrc + (s + 2) * 32);
            stg[s & 1][1] = *(const float4*)(tsrc + (s + 2) * 32 + 4);
            stg[s & 1][2] = *(const float4*)(rsrc + (s + 2) * 32);
            stg[s & 1][3] = *(const float4*)(rsrc + (s + 2) * 32 + 4);
        }
        acc_tt = __builtin_amdgcn_mfma_f32_16x16x32_f16(tf, tf, acc_tt, 0, 0, 0);
        acc_tr = __builtin_amdgcn_mfma_f32_16x16x32_f16(tf, rf, acc_tr, 0, 0, 0);
        acc_rr = __builtin_amdgcn_mfma_f32_16x16x32_f16(rf, rf, acc_rr, 0, 0, 0);
    }

    // C/D layout (m89): col = l&15, row index = kg*4 + r.
    const int m = row;
#pragma unroll
    for (int r = 0; r < 4; ++r) {
        const int n = kg * 4 + r;
        redTT[w][n * 16 + m] = acc_tt[r];
        redTR[w][n * 16 + m] = acc_tr[r];
    }
    if ((m >> 2) == kg) redRR[w][m] = acc_rr[m & 3];
    __syncthreads();

    // combine the 4 wave partials; one thread per Gram element
    const int n  = t >> 4;
    const int mm = t & 15;
    const float tt = redTT[0][t] + redTT[1][t] + redTT[2][t] + redTT[3][t];
    const float tr = redTR[0][t] + redTR[1][t] + redTR[2][t] + redTR[3][t];

    if (slot != 6) {
        float* slotp = ws + (size_t)(b * 6 + slot) * 528;
        slotp[n * 32 + mm]      = tt;
        slotp[n * 32 + 16 + mm] = tr;
        if (t < 16)
            slotp[512 + t] = redRR[0][t] + redRR[1][t] + redRR[2][t] + redRR[3][t];
        return;
    }

    // ---- slot 6 (level 2): finish the loss in-kernel ----
    Gs[n][mm]      = tt;
    Gs[n][16 + mm] = tr;
    if (t < 16)
        rn2[t] = redRR[0][t] + redRR[1][t] + redRR[2][t] + redRR[3][t];
    __syncthreads();

    if (t < 16) {
        tnS[t] = fmaxf(sqrtf(Gs[t][t]), NTX_EPS);
        rnS[t] = fmaxf(sqrtf(rn2[t]), NTX_EPS);
    }
    __syncthreads();

    float loss = 0.f;
    if (t < 16) {
        const int nn = t;
        const float itn = 2.0f / tnS[nn];        // includes 1/temperature
        float lg[32];
#pragma unroll
        for (int j = 0; j < 16; ++j)
            lg[j] = Gs[nn][16 + j] * itn / rnS[j];     // s_tr row
#pragma unroll
        for (int k = 0; k < 16; ++k)
            lg[16 + k] = Gs[nn][k] * itn / tnS[k];     // s_tt row
        const float pos = lg[nn];
        float mx = -3.4e38f;
#pragma unroll
        for (int j = 0; j < 32; ++j)
            mx = (j == 16 + nn) ? mx : fmaxf(mx, lg[j]);   // exclude tt diag
        float sm = 0.f;
#pragma unroll
        for (int j = 0; j < 32; ++j)
            sm += (j == 16 + nn) ? 0.f : expf(lg[j] - mx);
        loss = logf(sm) + mx - pos;
    }
    // lanes 0..15 live in wave 0; other waves contribute 0 and don't write
    loss += __shfl_xor(loss, 1, 64);
    loss += __shfl_xor(loss, 2, 64);
    loss += __shfl_xor(loss, 4, 64);
    loss += __shfl_xor(loss, 8, 64);
    if (t == 0) atomicAdd(out, loss * (1.0f / 512.0f));
}

// Kernel 2: sum partial Grams for levels 0/1 and do the logsumexp.
// grid = B*2 (b = bid>>1, lvl = bid&1), block = 64.
__global__ __launch_bounds__(64)
void ntxent_finish(const float* __restrict__ ws, float* __restrict__ out)
{
    __shared__ float G[16][33];
    __shared__ float rn2s[16];
    __shared__ float tn[16], rn[16];

    const int bid = blockIdx.x;
    const int b   = bid >> 1;
    const int lvl = bid & 1;
    const int base = b * 6 + (lvl ? 4 : 0);
    const int cnt  = lvl ? 2 : 4;
    const int l = threadIdx.x;

    for (int e = l; e < 512; e += 64) {
        float s = 0.f;
        for (int c = 0; c < cnt; ++c) s += ws[(size_t)(base + c) * 528 + e];
        G[e >> 5][e & 31] = s;
    }
    if (l < 16) {
        float s = 0.f;
        for (int c = 0; c < cnt; ++c) s += ws[(size_t)(base + c) * 528 + 512 + l];
        rn2s[l] = s;
    }
    __syncthreads();
    if (l < 16) {
        tn[l] = fmaxf(sqrtf(G[l][l]), NTX_EPS);
        rn[l] = fmaxf(sqrtf(rn2s[l]), NTX_EPS);
    }
    __syncthreads();

    float loss = 0.f;
    if (l < 16) {
        const int n = l;
        const float itn = 2.0f / tn[n];
        float lg[32];
#pragma unroll
        for (int j = 0; j < 16; ++j)
            lg[j] = G[n][16 + j] * itn / rn[j];
#pragma unroll
        for (int k = 0; k < 16; ++k)
            lg[16 + k] = G[n][k] * itn / tn[k];
        const float pos = lg[n];
        float mx = -3.4e38f;
#pragma unroll
        for (int j = 0; j < 32; ++j)
            mx = (j == 16 + n) ? mx : fmaxf(mx, lg[j]);
        float sm = 0.f;
#pragma unroll
        for (int j = 0; j < 32; ++j)
            sm += (j == 16 + n) ? 0.f : expf(lg[j] - mx);
        loss = logf(sm) + mx - pos;
    }
    loss += __shfl_xor(loss, 1, 64);
    loss += __shfl_xor(loss, 2, 64);
    loss += __shfl_xor(loss, 4, 64);
    loss += __shfl_xor(loss, 8, 64);
    if (l == 0) atomicAdd(out, loss * (1.0f / 512.0f));
}

extern "C" void kernel_launch(void* const* d_in, const int* in_sizes, int n_in,
                              void* d_out, int out_size, void* d_ws, size_t ws_size,
                              hipStream_t stream) {
    const float* ts0 = (const float*)d_in[0];
    const float* rs0 = (const float*)d_in[1];
    const float* ts1 = (const float*)d_in[2];
    const float* rs1 = (const float*)d_in[3];
    const float* ts2 = (const float*)d_in[4];
    const float* rs2 = (const float*)d_in[5];
    float* out = (float*)d_out;
    float* ws  = (float*)d_ws;

    hipMemsetAsync(out, 0, sizeof(float), stream);

    const int B = in_sizes[0] / (16 * 4096);   // 256
    hipLaunchKernelGGL(ntxent_partial, dim3(B * 7), dim3(256), 0, stream,
                       ts0, rs0, ts1, rs1, ts2, rs2, ws, out);
    hipLaunchKernelGGL(ntxent_finish, dim3(B * 2), dim3(64), 0, stream,
                       ws, out);
}

// Round 9
// 67.784 us; speedup vs baseline: 1.0027x; 1.0027x over previous
//
#include <hip/hip_runtime.h>
#include <math.h>

#define NTX_EPS 1e-8f

typedef __fp16 half8 __attribute__((ext_vector_type(8)));
typedef __fp16 half2v __attribute__((ext_vector_type(2)));
typedef float f32x4 __attribute__((ext_vector_type(4)));

union H8 { half8 v8; half2v v2[4]; };

__device__ __forceinline__ half8 pack8(const float4& a, const float4& b) {
    H8 u;
    u.v2[0] = __builtin_amdgcn_cvt_pkrtz(a.x, a.y);
    u.v2[1] = __builtin_amdgcn_cvt_pkrtz(a.z, a.w);
    u.v2[2] = __builtin_amdgcn_cvt_pkrtz(b.x, b.y);
    u.v2[3] = __builtin_amdgcn_cvt_pkrtz(b.z, b.w);
    return u.v8;
}

// Kernel 1: 1792 blocks x 256 threads (4 waves). Block = (b, slot):
// slot 0..3 -> lvl0 d-range slot*1024; 4..5 -> lvl1; 6 -> lvl2.
// Wave w owns d-sub-range w*256 (8 K-steps of 32). Register-only MFMA Gram
// (verified absmax=0): lane l feeds row l&15, k-chunk (l>>4)*8; one f16x8
// register is both A and B operand; mfma(t,t)/(t,r)/(r,r).
// R8 lesson: ping-pong staging let the allocator collapse to 32 VGPR and
// serialize loads (~4 in flight). This round: ALL 32 float4 loads issued as
// one dependence-free burst into 32 distinct registers (32KB/wave in flight),
// then one wait cascade + 24 MFMAs. MLP per CU ~256 loads, not occupancy,
// is the lever (L3-warm runs were equally slow -> latency-bound).
__global__ __launch_bounds__(256)
void ntxent_partial(const float* __restrict__ ts0, const float* __restrict__ rs0,
                    const float* __restrict__ ts1, const float* __restrict__ rs1,
                    const float* __restrict__ ts2, const float* __restrict__ rs2,
                    float* __restrict__ ws, float* __restrict__ out)
{
    __shared__ float redTT[4][256];
    __shared__ float redTR[4][256];
    __shared__ float redRR[4][16];
    __shared__ float Gs[16][33];
    __shared__ float rn2[16], tnS[16], rnS[16];

    const int bid  = blockIdx.x;
    const int b    = bid / 7;
    const int slot = bid % 7;

    const float* tp; const float* rp; int D; int chunk0;
    if (slot < 4)      { tp = ts0; rp = rs0; D = 4096; chunk0 = slot; }
    else if (slot < 6) { tp = ts1; rp = rs1; D = 2048; chunk0 = slot - 4; }
    else               { tp = ts2; rp = rs2; D = 1024; chunk0 = 0; }

    const int t   = threadIdx.x;
    const int w   = t >> 6;       // wave 0..3
    const int l   = t & 63;
    const int row = l & 15;       // Gram row/col this lane feeds
    const int kg  = l >> 4;       // k-group 0..3

    const size_t base = (size_t)b * 16 * D + (size_t)row * D
                      + (size_t)chunk0 * 1024 + (size_t)w * 256 + (size_t)kg * 8;
    const float* tsrc = tp + base;
    const float* rsrc = rp + base;

    // ---- one dependence-free burst: 32 independent float4 loads ----
    float4 T0[8], T1[8], R0[8], R1[8];
#pragma unroll
    for (int s = 0; s < 8; ++s) {
        T0[s] = *(const float4*)(tsrc + s * 32);
        T1[s] = *(const float4*)(tsrc + s * 32 + 4);
        R0[s] = *(const float4*)(rsrc + s * 32);
        R1[s] = *(const float4*)(rsrc + s * 32 + 4);
    }

    f32x4 acc_tt = {0.f, 0.f, 0.f, 0.f};
    f32x4 acc_tr = {0.f, 0.f, 0.f, 0.f};
    f32x4 acc_rr = {0.f, 0.f, 0.f, 0.f};

#pragma unroll
    for (int s = 0; s < 8; ++s) {
        half8 tf = pack8(T0[s], T1[s]);
        half8 rf = pack8(R0[s], R1[s]);
        acc_tt = __builtin_amdgcn_mfma_f32_16x16x32_f16(tf, tf, acc_tt, 0, 0, 0);
        acc_tr = __builtin_amdgcn_mfma_f32_16x16x32_f16(tf, rf, acc_tr, 0, 0, 0);
        acc_rr = __builtin_amdgcn_mfma_f32_16x16x32_f16(rf, rf, acc_rr, 0, 0, 0);
    }

    // C/D layout (m89): col = l&15, row index = kg*4 + r.
    const int m = row;
#pragma unroll
    for (int r = 0; r < 4; ++r) {
        const int n = kg * 4 + r;
        redTT[w][n * 16 + m] = acc_tt[r];
        redTR[w][n * 16 + m] = acc_tr[r];
    }
    if ((m >> 2) == kg) redRR[w][m] = acc_rr[m & 3];
    __syncthreads();

    // combine the 4 wave partials; one thread per Gram element
    const int n  = t >> 4;
    const int mm = t & 15;
    const float tt = redTT[0][t] + redTT[1][t] + redTT[2][t] + redTT[3][t];
    const float tr = redTR[0][t] + redTR[1][t] + redTR[2][t] + redTR[3][t];

    if (slot != 6) {
        float* slotp = ws + (size_t)(b * 6 + slot) * 528;
        slotp[n * 32 + mm]      = tt;
        slotp[n * 32 + 16 + mm] = tr;
        if (t < 16)
            slotp[512 + t] = redRR[0][t] + redRR[1][t] + redRR[2][t] + redRR[3][t];
        return;
    }

    // ---- slot 6 (level 2): finish the loss in-kernel ----
    Gs[n][mm]      = tt;
    Gs[n][16 + mm] = tr;
    if (t < 16)
        rn2[t] = redRR[0][t] + redRR[1][t] + redRR[2][t] + redRR[3][t];
    __syncthreads();

    if (t < 16) {
        tnS[t] = fmaxf(sqrtf(Gs[t][t]), NTX_EPS);
        rnS[t] = fmaxf(sqrtf(rn2[t]), NTX_EPS);
    }
    __syncthreads();

    float loss = 0.f;
    if (t < 16) {
        const int nn = t;
        const float itn = 2.0f / tnS[nn];        // includes 1/temperature
        float lg[32];
#pragma unroll
        for (int j = 0; j < 16; ++j)
            lg[j] = Gs[nn][16 + j] * itn / rnS[j];     // s_tr row
#pragma unroll
        for (int k = 0; k < 16; ++k)
            lg[16 + k] = Gs[nn][k] * itn / tnS[k];     // s_tt row
        const float pos = lg[nn];
        float mx = -3.4e38f;
#pragma unroll
        for (int j = 0; j < 32; ++j)
            mx = (j == 16 + nn) ? mx : fmaxf(mx, lg[j]);   // exclude tt diag
        float sm = 0.f;
#pragma unroll
        for (int j = 0; j < 32; ++j)
            sm += (j == 16 + nn) ? 0.f : expf(lg[j] - mx);
        loss = logf(sm) + mx - pos;
    }
    loss += __shfl_xor(loss, 1, 64);
    loss += __shfl_xor(loss, 2, 64);
    loss += __shfl_xor(loss, 4, 64);
    loss += __shfl_xor(loss, 8, 64);
    if (t == 0) atomicAdd(out, loss * (1.0f / 512.0f));
}

// Kernel 2: sum partial Grams for levels 0/1 and do the logsumexp.
// grid = B*2 (b = bid>>1, lvl = bid&1), block = 64.
__global__ __launch_bounds__(64)
void ntxent_finish(const float* __restrict__ ws, float* __restrict__ out)
{
    __shared__ float G[16][33];
    __shared__ float rn2s[16];
    __shared__ float tn[16], rn[16];

    const int bid = blockIdx.x;
    const int b   = bid >> 1;
    const int lvl = bid & 1;
    const int base = b * 6 + (lvl ? 4 : 0);
    const int cnt  = lvl ? 2 : 4;
    const int l = threadIdx.x;

    for (int e = l; e < 512; e += 64) {
        float s = 0.f;
        for (int c = 0; c < cnt; ++c) s += ws[(size_t)(base + c) * 528 + e];
        G[e >> 5][e & 31] = s;
    }
    if (l < 16) {
        float s = 0.f;
        for (int c = 0; c < cnt; ++c) s += ws[(size_t)(base + c) * 528 + 512 + l];
        rn2s[l] = s;
    }
    __syncthreads();
    if (l < 16) {
        tn[l] = fmaxf(sqrtf(G[l][l]), NTX_EPS);
        rn[l] = fmaxf(sqrtf(rn2s[l]), NTX_EPS);
    }
    __syncthreads();

    float loss = 0.f;
    if (l < 16) {
        const int n = l;
        const float itn = 2.0f / tn[n];
        float lg[32];
#pragma unroll
        for (int j = 0; j < 16; ++j)
            lg[j] = G[n][16 + j] * itn / rn[j];
#pragma unroll
        for (int k = 0; k < 16; ++k)
            lg[16 + k] = G[n][k] * itn / tn[k];
        const float pos = lg[n];
        float mx = -3.4e38f;
#pragma unroll
        for (int j = 0; j < 32; ++j)
            mx = (j == 16 + n) ? mx : fmaxf(mx, lg[j]);
        float sm = 0.f;
#pragma unroll
        for (int j = 0; j < 32; ++j)
            sm += (j == 16 + n) ? 0.f : expf(lg[j] - mx);
        loss = logf(sm) + mx - pos;
    }
    loss += __shfl_xor(loss, 1, 64);
    loss += __shfl_xor(loss, 2, 64);
    loss += __shfl_xor(loss, 4, 64);
    loss += __shfl_xor(loss, 8, 64);
    if (l == 0) atomicAdd(out, loss * (1.0f / 512.0f));
}

extern "C" void kernel_launch(void* const* d_in, const int* in_sizes, int n_in,
                              void* d_out, int out_size, void* d_ws, size_t ws_size,
                              hipStream_t stream) {
    const float* ts0 = (const float*)d_in[0];
    const float* rs0 = (const float*)d_in[1];
    const float* ts1 = (const float*)d_in[2];
    const float* rs1 = (const float*)d_in[3];
    const float* ts2 = (const float*)d_in[4];
    const float* rs2 = (const float*)d_in[5];
    float* out = (float*)d_out;
    float* ws  = (float*)d_ws;

    hipMemsetAsync(out, 0, sizeof(float), stream);

    const int B = in_sizes[0] / (16 * 4096);   // 256
    hipLaunchKernelGGL(ntxent_partial, dim3(B * 7), dim3(256), 0, stream,
                       ts0, rs0, ts1, rs1, ts2, rs2, ws, out);
    hipLaunchKernelGGL(ntxent_finish, dim3(B * 2), dim3(64), 0, stream,
                       ws, out);
}